// Round 2
// baseline (7884.419 us; speedup 1.0000x reference)
//
#include <hip/hip_runtime.h>
#include <hip/hip_bf16.h>

typedef _Float16 f16;
typedef _Float16 f16x8 __attribute__((ext_vector_type(8)));
typedef _Float16 f16x4 __attribute__((ext_vector_type(4)));
typedef float f32x4 __attribute__((ext_vector_type(4)));

#define B_ 64
#define T_ 32
#define L_ 49
#define F_ 512
#define H_ 512
#define A_ 256
#define E_ 256
#define V_ 32000
#define G4 2048   // 4*H
#define NBLK 128  // persistent kernel grid

// ---------------------------------------------------------------- converts
__global__ void k_cvt_f16(const float* __restrict__ x, f16* __restrict__ y, int n4) {
    int i = blockIdx.x * 256 + threadIdx.x;
    if (i < n4) {
        float4 v = ((const float4*)x)[i];
        f16x4 h = {(f16)v.x, (f16)v.y, (f16)v.z, (f16)v.w};
        ((f16x4*)y)[i] = h;
    }
}

// transpose+convert: x f32 [R][C] -> y f16 [C][R]; grid (C/32, R/32), 256 thr
__global__ void k_tcvt(const float* __restrict__ x, f16* __restrict__ y, int R, int C) {
    __shared__ float ls[32][33];
    int c0 = blockIdx.x * 32, r0 = blockIdx.y * 32;
    int tid = threadIdx.x;
    int rr = tid >> 3, cs = (tid & 7) * 4;
    float4 v = *(const float4*)&x[(size_t)(r0 + rr) * C + c0 + cs];
    ls[rr][cs] = v.x; ls[rr][cs + 1] = v.y; ls[rr][cs + 2] = v.z; ls[rr][cs + 3] = v.w;
    __syncthreads();
    int cr = tid >> 3, rs = (tid & 7) * 4;
    f16x4 o = {(f16)ls[rs][cr], (f16)ls[rs + 1][cr], (f16)ls[rs + 2][cr], (f16)ls[rs + 3][cr]};
    *(f16x4*)&y[(size_t)(c0 + cr) * R + r0 + rs] = o;
}

// embedding gather -> fp16, row r = b*T + t
__global__ void k_emb(const float* __restrict__ emb, const int* __restrict__ cap,
                      f16* __restrict__ out) {
    int r = blockIdx.x;
    int tok = cap[r];
    out[(size_t)r * E_ + threadIdx.x] = (f16)emb[(size_t)tok * E_ + threadIdx.x];
}

// ---------------------------------------------------------------- init h0/c0
__global__ void k_init(const float* __restrict__ feats,
                       const float* __restrict__ Wh, const float* __restrict__ bh,
                       const float* __restrict__ Wc, const float* __restrict__ bc,
                       float* __restrict__ hbuf, f16* __restrict__ h16rec,
                       float* __restrict__ c_cur) {
    __shared__ float mean[F_];
    int b = blockIdx.x, tid = threadIdx.x;
    for (int f = tid; f < F_; f += 256) {
        float s = 0.f;
        for (int l = 0; l < L_; ++l) s += feats[((size_t)b * L_ + l) * F_ + f];
        mean[f] = s * (1.f / 49.f);
    }
    __syncthreads();
    for (int h = tid; h < H_; h += 256) {
        float a = bh[h], c = bc[h];
        for (int k = 0; k < F_; ++k) {
            float m = mean[k];
            a += m * Wh[k * H_ + h];
            c += m * Wc[k * H_ + h];
        }
        hbuf[b * H_ + h] = a;
        h16rec[b * H_ + h] = (f16)a;
        c_cur[b * H_ + h] = c;
    }
}

// ---------------------------------------------------------------- feat_proj (fp32)
__global__ void k_featproj(const float* __restrict__ feats, const float* __restrict__ Wf,
                           const float* __restrict__ bf, float* __restrict__ out) {
    __shared__ float fs[16][F_];
    int r0 = blockIdx.x * 16, tid = threadIdx.x;
    for (int i = tid; i < 16 * F_; i += 256)
        fs[i >> 9][i & 511] = feats[(size_t)r0 * F_ + i];
    __syncthreads();
    float acc[16];
#pragma unroll
    for (int r = 0; r < 16; ++r) acc[r] = 0.f;
    for (int k = 0; k < F_; ++k) {
        float w = Wf[k * A_ + tid];
#pragma unroll
        for (int r = 0; r < 16; ++r) acc[r] += fs[r][k] * w;
    }
    float bb = bf[tid];
#pragma unroll
    for (int r = 0; r < 16; ++r) out[(size_t)(r0 + r) * A_ + tid] = acc[r] + bb;
}

// ---------------------------------------------------------------- 128x128 MFMA GEMM
// C(MxN,f32) = A(MxK,f16,[row][k]) @ Bt(NxK,f16,[col][k])^T  [+bias0+bias1]
// 256 thr = 4 waves (2x2), wave tile 64x64 = 4x4 mfma 16x16x32. K%32==0, N%128==0.
struct Smem128 { f16 As[128][40]; f16 Bs[128][40]; };

__global__ __launch_bounds__(256) void k_gemm128(
    const f16* __restrict__ A, int lda, const f16* __restrict__ Bt, int ldb,
    float* __restrict__ C, int ldc, int M, int K, int mtiles,
    const float* __restrict__ bias0, const float* __restrict__ bias1) {
    __shared__ Smem128 sm;
    int bid = blockIdx.x;
    int m0 = (bid % mtiles) * 128, n0 = (bid / mtiles) * 128;
    int tid = threadIdx.x, lane = tid & 63, wave = tid >> 6;
    int wr = (wave >> 1) * 64, wc = (wave & 1) * 64;
    int frow = lane & 15, fk = (lane >> 4) * 8;
    int ra = tid >> 2, ka = (tid & 3) * 8;
    f32x4 acc[4][4];
#pragma unroll
    for (int i = 0; i < 4; ++i)
#pragma unroll
        for (int j = 0; j < 4; ++j) { acc[i][j][0]=0.f; acc[i][j][1]=0.f; acc[i][j][2]=0.f; acc[i][j][3]=0.f; }

    for (int k0 = 0; k0 < K; k0 += 32) {
        f16x8 a0 = *(const f16x8*)&A[(size_t)(m0 + ra) * lda + k0 + ka];
        f16x8 a1 = *(const f16x8*)&A[(size_t)(m0 + 64 + ra) * lda + k0 + ka];
        f16x8 b0 = *(const f16x8*)&Bt[(size_t)(n0 + ra) * ldb + k0 + ka];
        f16x8 b1 = *(const f16x8*)&Bt[(size_t)(n0 + 64 + ra) * ldb + k0 + ka];
        __syncthreads();
        *(f16x8*)&sm.As[ra][ka] = a0;
        *(f16x8*)&sm.As[64 + ra][ka] = a1;
        *(f16x8*)&sm.Bs[ra][ka] = b0;
        *(f16x8*)&sm.Bs[64 + ra][ka] = b1;
        __syncthreads();
        f16x8 av[4], bv[4];
#pragma unroll
        for (int i = 0; i < 4; ++i) {
            av[i] = *(f16x8*)&sm.As[wr + i * 16 + frow][fk];
            bv[i] = *(f16x8*)&sm.Bs[wc + i * 16 + frow][fk];
        }
#pragma unroll
        for (int mi = 0; mi < 4; ++mi)
#pragma unroll
            for (int ni = 0; ni < 4; ++ni)
                acc[mi][ni] = __builtin_amdgcn_mfma_f32_16x16x32_f16(av[mi], bv[ni], acc[mi][ni], 0, 0, 0);
    }
    int rq = (lane >> 4) * 4;
#pragma unroll
    for (int mi = 0; mi < 4; ++mi)
#pragma unroll
        for (int ni = 0; ni < 4; ++ni) {
            int cc = n0 + wc + ni * 16 + frow;
            float badd = (bias0 ? bias0[cc] : 0.f) + (bias1 ? bias1[cc] : 0.f);
#pragma unroll
            for (int r = 0; r < 4; ++r) {
                int rr = m0 + wr + mi * 16 + rq + r;
                if (rr < M) C[(size_t)rr * ldc + cc] = acc[mi][ni][r] + badd;
            }
        }
}

// ---------------------------------------------------------------- persistent step kernel
struct AttSm { float h_s[H_]; float ea[A_]; float sc[64]; };
struct Gemm64Sm { f16 As[64][40]; f16 Bs[32][40]; };
union StepSm { AttSm att; Gemm64Sm g; float al[L_]; };

__device__ __forceinline__ void gbar(unsigned* bar, unsigned target) {
    __syncthreads();
    if (threadIdx.x == 0) {
        __hip_atomic_fetch_add(bar, 1u, __ATOMIC_ACQ_REL, __HIP_MEMORY_SCOPE_AGENT);
        while (__hip_atomic_load(bar, __ATOMIC_ACQUIRE, __HIP_MEMORY_SCOPE_AGENT) < target) {
            __builtin_amdgcn_s_sleep(1);
        }
    }
    __syncthreads();
}

__global__ __launch_bounds__(256) void k_steps(
    const f16* __restrict__ WhhT, const float* __restrict__ featproj,
    const float* __restrict__ Whid, const float* __restrict__ bhid,
    const float* __restrict__ Wscore, const float* __restrict__ bscore,
    const float* __restrict__ embproj, const float* __restrict__ featproj2,
    float* __restrict__ hbuf, f16* __restrict__ h16rec, f16* __restrict__ h16log,
    float* __restrict__ c_cur, float* __restrict__ alpha_ws, float* __restrict__ hWhh,
    float* __restrict__ out_alpha, unsigned* __restrict__ bar) {
    __shared__ StepSm sm;
    int bid = blockIdx.x, tid = threadIdx.x;
    int lane = tid & 63, wave = tid >> 6;
    unsigned ep = 0;

    for (int t = 0; t < T_; ++t) {
        // ---------------- phase A ----------------
        if (bid < 64) {
            // attention for batch b
            int b = bid;
            const float* h = hbuf + ((size_t)t * B_ + b) * H_;
            for (int i = tid; i < H_; i += 256) sm.att.h_s[i] = h[i];
            __syncthreads();
            {
                float acc = bhid[tid];
#pragma unroll 8
                for (int k = 0; k < H_; ++k) acc += sm.att.h_s[k] * Whid[k * A_ + tid];
                sm.att.ea[tid] = acc;
            }
            __syncthreads();
            for (int l = wave; l < L_; l += 4) {
                const float* fp = featproj + ((size_t)b * L_ + l) * A_;
                float p = 0.f;
                for (int j = lane; j < A_; j += 64) p += tanhf(fp[j] + sm.att.ea[j]) * Wscore[j];
#pragma unroll
                for (int off = 32; off > 0; off >>= 1) p += __shfl_xor(p, off);
                if (lane == 0) sm.att.sc[l] = p;
            }
            __syncthreads();
            if (tid < 64) {
                float v = (tid < L_) ? sm.att.sc[tid] + bscore[0] : -3.4e38f;
                float m = v;
#pragma unroll
                for (int off = 32; off > 0; off >>= 1) m = fmaxf(m, __shfl_xor(m, off));
                float e = (tid < L_) ? expf(v - m) : 0.f;
                float s = e;
#pragma unroll
                for (int off = 32; off > 0; off >>= 1) s += __shfl_xor(s, off);
                if (tid < L_) {
                    float al = e / s;
                    alpha_ws[b * L_ + tid] = al;
                    out_alpha[((size_t)b * T_ + t) * L_ + tid] = al;
                }
            }
        } else {
            // hWhh = h16rec[t] @ WhhT^T : M=64, block tile N=32, K=512
            int n0 = (bid - 64) * 32;
            const f16* Asrc = h16rec + (size_t)t * B_ * H_;
            int ra = tid >> 2, ks = (tid & 3) * 8;
            int wr = (wave & 1) * 32, wc = (wave >> 1) * 16;
            int frow = lane & 15, fk = (lane >> 4) * 8;
            f32x4 acc2[2];
            acc2[0][0]=0.f; acc2[0][1]=0.f; acc2[0][2]=0.f; acc2[0][3]=0.f;
            acc2[1][0]=0.f; acc2[1][1]=0.f; acc2[1][2]=0.f; acc2[1][3]=0.f;
            for (int k0 = 0; k0 < H_; k0 += 32) {
                f16x8 a = *(const f16x8*)&Asrc[(size_t)ra * H_ + k0 + ks];
                f16x8 bwv;
                if (tid < 128) bwv = *(const f16x8*)&WhhT[(size_t)(n0 + ra) * H_ + k0 + ks];
                __syncthreads();
                *(f16x8*)&sm.g.As[ra][ks] = a;
                if (tid < 128) *(f16x8*)&sm.g.Bs[ra][ks] = bwv;
                __syncthreads();
                f16x8 av0 = *(f16x8*)&sm.g.As[wr + frow][fk];
                f16x8 av1 = *(f16x8*)&sm.g.As[wr + 16 + frow][fk];
                f16x8 bv = *(f16x8*)&sm.g.Bs[wc + frow][fk];
                acc2[0] = __builtin_amdgcn_mfma_f32_16x16x32_f16(av0, bv, acc2[0], 0, 0, 0);
                acc2[1] = __builtin_amdgcn_mfma_f32_16x16x32_f16(av1, bv, acc2[1], 0, 0, 0);
            }
            int rq = (lane >> 4) * 4;
#pragma unroll
            for (int mi = 0; mi < 2; ++mi)
#pragma unroll
                for (int r = 0; r < 4; ++r) {
                    int rr = wr + mi * 16 + rq + r;
                    hWhh[(size_t)rr * G4 + n0 + wc + frow] = acc2[mi][r];
                }
        }
        ++ep; gbar(bar, ep * NBLK);

        // ---------------- phase B: gates, all 128 blocks ----------------
        {
            int b = bid >> 1, jh = bid & 1;
            if (tid < L_) sm.al[tid] = alpha_ws[b * L_ + tid];
            __syncthreads();
            int j = jh * 256 + tid;
            size_t eb = ((size_t)b * T_ + t) * G4 + j;
            float gi = embproj[eb], gf = embproj[eb + 512], gg = embproj[eb + 1024], go = embproj[eb + 1536];
            size_t wb = (size_t)b * G4 + j;
            gi += hWhh[wb]; gf += hWhh[wb + 512]; gg += hWhh[wb + 1024]; go += hWhh[wb + 1536];
            for (int l = 0; l < L_; ++l) {
                float a = sm.al[l];
                const float* fp = featproj2 + ((size_t)b * L_ + l) * G4 + j;
                gi += a * fp[0]; gf += a * fp[512]; gg += a * fp[1024]; go += a * fp[1536];
            }
            float ii = 1.f / (1.f + expf(-gi));
            float ff = 1.f / (1.f + expf(-gf));
            float oo = 1.f / (1.f + expf(-go));
            float g = tanhf(gg);
            int cidx = b * H_ + j;
            float c = ff * c_cur[cidx] + ii * g;
            float hh = oo * tanhf(c);
            c_cur[cidx] = c;
            hbuf[(size_t)(t + 1) * B_ * H_ + cidx] = hh;
            f16 h6 = (f16)hh;
            h16rec[(size_t)(t + 1) * B_ * H_ + cidx] = h6;
            h16log[((size_t)b * T_ + t) * H_ + j] = h6;
        }
        ++ep; gbar(bar, ep * NBLK);
    }
}

// ---------------------------------------------------------------- launch
extern "C" void kernel_launch(void* const* d_in, const int* in_sizes, int n_in,
                              void* d_out, int out_size, void* d_ws, size_t ws_size,
                              hipStream_t stream) {
    const float* image_feats = (const float*)d_in[0];
    const int*   caption     = (const int*)d_in[1];
    const float* embedding   = (const float*)d_in[2];
    const float* W_init_h    = (const float*)d_in[3];
    const float* b_init_h    = (const float*)d_in[4];
    const float* W_init_c    = (const float*)d_in[5];
    const float* b_init_c    = (const float*)d_in[6];
    const float* W_feat      = (const float*)d_in[7];
    const float* b_feat      = (const float*)d_in[8];
    const float* W_hid       = (const float*)d_in[9];
    const float* b_hid       = (const float*)d_in[10];
    const float* W_score     = (const float*)d_in[11];
    const float* b_score     = (const float*)d_in[12];
    const float* W_ih        = (const float*)d_in[13];
    const float* b_ih        = (const float*)d_in[14];
    const float* W_hh        = (const float*)d_in[15];
    const float* b_hh        = (const float*)d_in[16];
    const float* W_out       = (const float*)d_in[17];
    const float* b_out       = (const float*)d_in[18];

    float* preds = (float*)d_out;                                   // (B,T,V)
    float* out_alpha = preds + (size_t)B_ * T_ * V_;                // (B,T,L)

    size_t off = 0;
    char* base = (char*)d_ws;
    auto carve = [&](size_t bytes) {
        void* p = base + off;
        off += (bytes + 255) & ~(size_t)255;
        return p;
    };
    const int MP = 3200;  // B*L=3136 padded to 25*128
    float* featproj2 = (float*)carve((size_t)MP * G4 * 4);          // 26.2 MB
    float* embproj   = (float*)carve((size_t)B_ * T_ * G4 * 4);     // 16.8 MB
    float* featproj  = (float*)carve((size_t)B_ * L_ * A_ * 4);     // 3.2 MB
    float* hbuf      = (float*)carve((size_t)(T_ + 1) * B_ * H_ * 4);
    float* c_cur     = (float*)carve((size_t)B_ * H_ * 4);
    float* hWhh      = (float*)carve((size_t)B_ * G4 * 4);
    float* alpha_ws  = (float*)carve((size_t)B_ * L_ * 4);
    unsigned* bar    = (unsigned*)carve(256);
    f16* feats16     = (f16*)carve((size_t)MP * F_ * 2);            // padded rows
    f16* embs16      = (f16*)carve((size_t)B_ * T_ * E_ * 2);
    f16* WihT        = (f16*)carve((size_t)G4 * (E_ + F_) * 2);     // [2048][768]
    f16* WhhT        = (f16*)carve((size_t)G4 * H_ * 2);            // [2048][512]
    f16* WoutT       = (f16*)carve((size_t)V_ * H_ * 2);            // [32000][512]
    f16* h16rec      = (f16*)carve((size_t)(T_ + 1) * B_ * H_ * 2);
    f16* h16log      = (f16*)carve((size_t)B_ * T_ * H_ * 2);
    (void)ws_size; (void)in_sizes; (void)n_in; (void)out_size;

    // weight transposes (f32 [R][C] -> f16 [C][R])
    hipLaunchKernelGGL(k_tcvt, dim3(G4 / 32, (E_ + F_) / 32), dim3(256), 0, stream,
                       W_ih, WihT, E_ + F_, G4);
    hipLaunchKernelGGL(k_tcvt, dim3(G4 / 32, H_ / 32), dim3(256), 0, stream,
                       W_hh, WhhT, H_, G4);
    hipLaunchKernelGGL(k_tcvt, dim3(V_ / 32, H_ / 32), dim3(256), 0, stream,
                       W_out, WoutT, H_, V_);
    {   // feats -> f16
        int n4 = (int)((size_t)B_ * L_ * F_ / 4);
        hipLaunchKernelGGL(k_cvt_f16, dim3((n4 + 255) / 256), dim3(256), 0, stream,
                           image_feats, feats16, n4);
    }
    hipLaunchKernelGGL(k_emb, dim3(B_ * T_), dim3(E_), 0, stream, embedding, caption, embs16);
    hipLaunchKernelGGL(k_init, dim3(B_), dim3(256), 0, stream,
                       image_feats, W_init_h, b_init_h, W_init_c, b_init_c,
                       hbuf, h16rec, c_cur);
    hipLaunchKernelGGL(k_featproj, dim3(B_ * L_ / 16), dim3(256), 0, stream,
                       image_feats, W_feat, b_feat, featproj);
    // featproj2 = feats @ W_ih[E:,:]  (M=3136(->3200), N=2048, K=512)
    hipLaunchKernelGGL(k_gemm128, dim3(25 * (G4 / 128)), dim3(256), 0, stream,
                       feats16, F_, WihT + E_, E_ + F_,
                       featproj2, G4, B_ * L_, F_, 25,
                       (const float*)nullptr, (const float*)nullptr);
    // embproj = embs @ W_ih[:E,:] + b_ih + b_hh  (M=2048, N=2048, K=256)
    hipLaunchKernelGGL(k_gemm128, dim3((B_ * T_ / 128) * (G4 / 128)), dim3(256), 0, stream,
                       embs16, E_, WihT, E_ + F_,
                       embproj, G4, B_ * T_, E_, B_ * T_ / 128,
                       b_ih, b_hh);
    // recurrence: one persistent kernel, 128 blocks, 64 global barriers
    hipMemsetAsync(bar, 0, 256, stream);
    hipLaunchKernelGGL(k_steps, dim3(NBLK), dim3(256), 0, stream,
                       WhhT, featproj, W_hid, b_hid, W_score, b_score,
                       embproj, featproj2, hbuf, h16rec, h16log,
                       c_cur, alpha_ws, hWhh, out_alpha, bar);
    // predictions = h16log @ W_out + b_out  (M=2048, N=32000, K=512)
    hipLaunchKernelGGL(k_gemm128, dim3((B_ * T_ / 128) * (V_ / 128)), dim3(256), 0, stream,
                       h16log, H_, WoutT, H_,
                       preds, V_, B_ * T_, H_, B_ * T_ / 128,
                       b_out, (const float*)nullptr);
}

// Round 3
// 1208.127 us; speedup vs baseline: 6.5262x; 6.5262x over previous
//
#include <hip/hip_runtime.h>
#include <hip/hip_bf16.h>

typedef _Float16 f16;
typedef _Float16 f16x8 __attribute__((ext_vector_type(8)));
typedef _Float16 f16x4 __attribute__((ext_vector_type(4)));
typedef _Float16 f16x2 __attribute__((ext_vector_type(2)));
typedef float f32x4 __attribute__((ext_vector_type(4)));

#define B_ 64
#define T_ 32
#define L_ 49
#define F_ 512
#define H_ 512
#define A_ 256
#define E_ 256
#define V_ 32000
#define G4 2048   // 4*H
#define SLOT 16   // flag padding: 16 uints = 64B

// ---------------------------------------------------------------- converts
__global__ void k_cvt_f16(const float* __restrict__ x, f16* __restrict__ y, int n4) {
    int i = blockIdx.x * 256 + threadIdx.x;
    if (i < n4) {
        float4 v = ((const float4*)x)[i];
        f16x4 h = {(f16)v.x, (f16)v.y, (f16)v.z, (f16)v.w};
        ((f16x4*)y)[i] = h;
    }
}

// transpose+convert: x f32 [R][C] -> y f16 [C][R]
__global__ void k_tcvt(const float* __restrict__ x, f16* __restrict__ y, int R, int C) {
    __shared__ float ls[32][33];
    int c0 = blockIdx.x * 32, r0 = blockIdx.y * 32;
    int tid = threadIdx.x;
    int rr = tid >> 3, cs = (tid & 7) * 4;
    float4 v = *(const float4*)&x[(size_t)(r0 + rr) * C + c0 + cs];
    ls[rr][cs] = v.x; ls[rr][cs + 1] = v.y; ls[rr][cs + 2] = v.z; ls[rr][cs + 3] = v.w;
    __syncthreads();
    int cr = tid >> 3, rs = (tid & 7) * 4;
    f16x4 o = {(f16)ls[rs][cr], (f16)ls[rs + 1][cr], (f16)ls[rs + 2][cr], (f16)ls[rs + 3][cr]};
    *(f16x4*)&y[(size_t)(c0 + cr) * R + r0 + rs] = o;
}

// W_hid f32 [512][256] -> k-pair packed f16x2 [256][256]
__global__ void k_pairs(const float* __restrict__ w, f16* __restrict__ out) {
    int k2 = blockIdx.x, a = threadIdx.x;
    out[(k2 * 256 + a) * 2]     = (f16)w[(2 * k2) * 256 + a];
    out[(k2 * 256 + a) * 2 + 1] = (f16)w[(2 * k2 + 1) * 256 + a];
}

// embedding gather -> fp16, row r = b*T + t
__global__ void k_emb(const float* __restrict__ emb, const int* __restrict__ cap,
                      f16* __restrict__ out) {
    int r = blockIdx.x;
    int tok = cap[r];
    out[(size_t)r * E_ + threadIdx.x] = (f16)emb[(size_t)tok * E_ + threadIdx.x];
}

// ---------------------------------------------------------------- init h0/c0
__global__ void k_init(const float* __restrict__ feats,
                       const float* __restrict__ Wh, const float* __restrict__ bh,
                       const float* __restrict__ Wc, const float* __restrict__ bc,
                       float* __restrict__ hbuf0, f16* __restrict__ h16rec,
                       float* __restrict__ c_cur) {
    __shared__ float mean[F_];
    int b = blockIdx.x, tid = threadIdx.x;
    for (int f = tid; f < F_; f += 256) {
        float s = 0.f;
        for (int l = 0; l < L_; ++l) s += feats[((size_t)b * L_ + l) * F_ + f];
        mean[f] = s * (1.f / 49.f);
    }
    __syncthreads();
    for (int h = tid; h < H_; h += 256) {
        float a = bh[h], c = bc[h];
        for (int k = 0; k < F_; ++k) {
            float m = mean[k];
            a += m * Wh[k * H_ + h];
            c += m * Wc[k * H_ + h];
        }
        hbuf0[b * H_ + h] = a;
        h16rec[b * H_ + h] = (f16)a;
        c_cur[b * H_ + h] = c;
    }
}

// ---------------------------------------------------------------- feat_proj (fp32)
__global__ void k_featproj(const float* __restrict__ feats, const float* __restrict__ Wf,
                           const float* __restrict__ bf, float* __restrict__ out) {
    __shared__ float fs[16][F_];
    int r0 = blockIdx.x * 16, tid = threadIdx.x;
    for (int i = tid; i < 16 * F_; i += 256)
        fs[i >> 9][i & 511] = feats[(size_t)r0 * F_ + i];
    __syncthreads();
    float acc[16];
#pragma unroll
    for (int r = 0; r < 16; ++r) acc[r] = 0.f;
    for (int k = 0; k < F_; ++k) {
        float w = Wf[k * A_ + tid];
#pragma unroll
        for (int r = 0; r < 16; ++r) acc[r] += fs[r][k] * w;
    }
    float bb = bf[tid];
#pragma unroll
    for (int r = 0; r < 16; ++r) out[(size_t)(r0 + r) * A_ + tid] = acc[r] + bb;
}

// ---------------------------------------------------------------- 128x128 MFMA GEMM
// MODE 0: C f32 [rr*ldc+cc] + bias   MODE 1: C f16 gate-permuted [(rr*512+(cc&511))*4+(cc>>9)]
struct Smem128 { f16 As[128][40]; f16 Bs[128][40]; };

template <int MODE>
__global__ __launch_bounds__(256) void k_gemm128(
    const f16* __restrict__ A, int lda, const f16* __restrict__ Bt, int ldb,
    void* __restrict__ Cv, int ldc, int M, int K, int mtiles,
    const float* __restrict__ bias0, const float* __restrict__ bias1) {
    __shared__ Smem128 sm;
    int bid = blockIdx.x;
    int m0 = (bid % mtiles) * 128, n0 = (bid / mtiles) * 128;
    int tid = threadIdx.x, lane = tid & 63, wave = tid >> 6;
    int wr = (wave >> 1) * 64, wc = (wave & 1) * 64;
    int frow = lane & 15, fk = (lane >> 4) * 8;
    int ra = tid >> 2, ka = (tid & 3) * 8;
    f32x4 acc[4][4];
#pragma unroll
    for (int i = 0; i < 4; ++i)
#pragma unroll
        for (int j = 0; j < 4; ++j) { acc[i][j][0]=0.f; acc[i][j][1]=0.f; acc[i][j][2]=0.f; acc[i][j][3]=0.f; }

    for (int k0 = 0; k0 < K; k0 += 32) {
        f16x8 a0 = *(const f16x8*)&A[(size_t)(m0 + ra) * lda + k0 + ka];
        f16x8 a1 = *(const f16x8*)&A[(size_t)(m0 + 64 + ra) * lda + k0 + ka];
        f16x8 b0 = *(const f16x8*)&Bt[(size_t)(n0 + ra) * ldb + k0 + ka];
        f16x8 b1 = *(const f16x8*)&Bt[(size_t)(n0 + 64 + ra) * ldb + k0 + ka];
        __syncthreads();
        *(f16x8*)&sm.As[ra][ka] = a0;
        *(f16x8*)&sm.As[64 + ra][ka] = a1;
        *(f16x8*)&sm.Bs[ra][ka] = b0;
        *(f16x8*)&sm.Bs[64 + ra][ka] = b1;
        __syncthreads();
        f16x8 av[4], bv[4];
#pragma unroll
        for (int i = 0; i < 4; ++i) {
            av[i] = *(f16x8*)&sm.As[wr + i * 16 + frow][fk];
            bv[i] = *(f16x8*)&sm.Bs[wc + i * 16 + frow][fk];
        }
#pragma unroll
        for (int mi = 0; mi < 4; ++mi)
#pragma unroll
            for (int ni = 0; ni < 4; ++ni)
                acc[mi][ni] = __builtin_amdgcn_mfma_f32_16x16x32_f16(av[mi], bv[ni], acc[mi][ni], 0, 0, 0);
    }
    int rq = (lane >> 4) * 4;
#pragma unroll
    for (int mi = 0; mi < 4; ++mi)
#pragma unroll
        for (int ni = 0; ni < 4; ++ni) {
            int cc = n0 + wc + ni * 16 + frow;
            float badd = (bias0 ? bias0[cc] : 0.f) + (bias1 ? bias1[cc] : 0.f);
#pragma unroll
            for (int r = 0; r < 4; ++r) {
                int rr = m0 + wr + mi * 16 + rq + r;
                if (rr < M) {
                    if (MODE == 0)
                        ((float*)Cv)[(size_t)rr * ldc + cc] = acc[mi][ni][r] + badd;
                    else
                        ((f16*)Cv)[((size_t)rr * 512 + (cc & 511)) * 4 + (cc >> 9)] =
                            (f16)(acc[mi][ni][r] + badd);
                }
            }
        }
}

// ---------------------------------------------------------------- persistent recurrence
struct GateSm {
    float fp[L_][A_];    // 50176 B
    float h[H_];         // 2 KB
    float c[H_];         // 2 KB
    float ea[A_];        // 1 KB
    float ws[A_];        // 1 KB
    float sc[64];
    float alpha[64];
};                       // 56832 B
struct GemmSm { f16 w[32][552]; };   // 35328 B (stride 552 f16 = 276 dw ≡ 20 mod 32 → 2-way only)

__device__ __forceinline__ void wait_all(const unsigned* flags, unsigned target) {
    int l = threadIdx.x & 63;
    const unsigned* p = flags + l * SLOT;
    int spins = 0;
    while (__hip_atomic_load(p, __ATOMIC_RELAXED, __HIP_MEMORY_SCOPE_AGENT) < target) {
        if (++spins > 24) __builtin_amdgcn_s_sleep(2);
    }
    __threadfence();   // acquire: make producers' data visible
}

__device__ __forceinline__ float sigm(float x) { return 1.f / (1.f + __expf(-x)); }
__device__ __forceinline__ float tanh_f(float x) { return 1.f - 2.f / (1.f + __expf(2.f * x)); }

__global__ __launch_bounds__(256, 1) void k_steps(
    const f16* __restrict__ WhhT, const float* __restrict__ featproj,
    const f16x2* __restrict__ Whidp, const float* __restrict__ b_hid,
    const float* __restrict__ W_score, const float* __restrict__ b_score,
    const f16* __restrict__ embprojP, const f16* __restrict__ featproj2P,
    const float* __restrict__ hbuf0, const float* __restrict__ c_cur,
    f16* __restrict__ h16rec, f16* __restrict__ h16log,
    float* __restrict__ hWhhP, float* __restrict__ out_alpha,
    unsigned* __restrict__ gateflag, unsigned* __restrict__ gemmflag) {
    __shared__ __align__(16) char smraw[sizeof(GateSm)];
    int bid = blockIdx.x, tid = threadIdx.x;

    if (bid < 64) {
        // ============ gate/attention block for batch b ============
        int b = bid;
        GateSm* S = (GateSm*)smraw;
        for (int i = tid; i < L_ * A_; i += 256)
            ((float*)S->fp)[i] = featproj[(size_t)b * L_ * A_ + i];
        for (int i = tid; i < H_; i += 256) {
            S->h[i] = hbuf0[b * H_ + i];
            S->c[i] = c_cur[b * H_ + i];
        }
        S->ws[tid] = W_score[tid];
        float bhid_r = b_hid[tid];
        float bsc = b_score[0];
        __syncthreads();

        const float2* h2 = (const float2*)S->h;
        int wv = tid >> 6, ln = tid & 63;

        for (int t = 0; t < T_; ++t) {
            // ---- ea = h @ W_hid + b_hid (thread = attn col) ----
            float acc = bhid_r;
#pragma unroll 8
            for (int k2 = 0; k2 < 256; ++k2) {
                f16x2 w = Whidp[k2 * 256 + tid];
                float2 hp = h2[k2];
                acc += hp.x * (float)w.x + hp.y * (float)w.y;
            }
            S->ea[tid] = acc;
            __syncthreads();
            // ---- scores ----
            for (int l = wv; l < L_; l += 4) {
                float p = 0.f;
#pragma unroll
                for (int q = 0; q < 4; ++q) {
                    int j = ln + q * 64;
                    p += tanh_f(S->fp[l][j] + S->ea[j]) * S->ws[j];
                }
#pragma unroll
                for (int off = 32; off > 0; off >>= 1) p += __shfl_xor(p, off);
                if (ln == 0) S->sc[l] = p;
            }
            __syncthreads();
            // ---- softmax (wave 0) ----
            if (tid < 64) {
                float v = (tid < L_) ? S->sc[tid] + bsc : -3.4e38f;
                float m = v;
#pragma unroll
                for (int off = 32; off > 0; off >>= 1) m = fmaxf(m, __shfl_xor(m, off));
                float e = (tid < L_) ? __expf(v - m) : 0.f;
                float s = e;
#pragma unroll
                for (int off = 32; off > 0; off >>= 1) s += __shfl_xor(s, off);
                if (tid < L_) {
                    float al = e / s;
                    S->alpha[tid] = al;
                    out_alpha[((size_t)b * T_ + t) * L_ + tid] = al;
                }
            }
            __syncthreads();
            // ---- wait recurrent matmul for this step ----
            wait_all(gemmflag, (unsigned)(t + 1));
            // ---- gates + pointwise; thread handles cols tid, tid+256 ----
#pragma unroll
            for (int half = 0; half < 2; ++half) {
                int j = tid + half * 256;
                float4 hw = *(const float4*)&hWhhP[((size_t)b * 512 + j) * 4];
                f16x4 ep = *(const f16x4*)&embprojP[(((size_t)b * T_ + t) * 512 + j) * 4];
                float gi = hw.x + (float)ep[0];
                float gf = hw.y + (float)ep[1];
                float gg = hw.z + (float)ep[2];
                float go = hw.w + (float)ep[3];
#pragma unroll 7
                for (int l = 0; l < L_; ++l) {
                    float a = S->alpha[l];
                    f16x4 fv = *(const f16x4*)&featproj2P[(((size_t)b * L_ + l) * 512 + j) * 4];
                    gi += a * (float)fv[0]; gf += a * (float)fv[1];
                    gg += a * (float)fv[2]; go += a * (float)fv[3];
                }
                float ii = sigm(gi), ff = sigm(gf), oo = sigm(go);
                float g = tanh_f(gg);
                float cn = ff * S->c[j] + ii * g;
                float hn = oo * tanh_f(cn);
                S->c[j] = cn;
                S->h[j] = hn;
                f16 h6 = (f16)hn;
                h16rec[((size_t)(t + 1) * B_ + b) * H_ + j] = h6;
                h16log[((size_t)b * T_ + t) * H_ + j] = h6;
            }
            __syncthreads();
            if (tid == 0) {
                __threadfence();
                __hip_atomic_store(&gateflag[b * SLOT], (unsigned)(t + 1),
                                   __ATOMIC_RELAXED, __HIP_MEMORY_SCOPE_AGENT);
            }
        }
    } else {
        // ============ hWhh GEMM block: 32-col slice of 4H ============
        int g = bid - 64;
        int n0 = g * 32;
        GemmSm* S = (GemmSm*)smraw;
        for (int idx = tid; idx < 32 * 64; idx += 256) {
            int r = idx >> 6, s = idx & 63;
            *(f16x8*)&S->w[r][s * 8] = *(const f16x8*)&WhhT[(size_t)(n0 + r) * H_ + s * 8];
        }
        __syncthreads();
        int wv = tid >> 6, lane = tid & 63;
        int frow = lane & 15, q = lane >> 4, fk = q * 8;
        int mbase = (wv >> 1) * 32, nt = (wv & 1) * 16;
        int col = n0 + nt + frow;
        int gate = col >> 9, cj = col & 511;
        int rq = q * 4;

        for (int t = 0; t < T_; ++t) {
            wait_all(gateflag, (unsigned)t);
            const f16* hs = h16rec + (size_t)t * B_ * H_;
            f32x4 acc0 = {0.f, 0.f, 0.f, 0.f}, acc1 = {0.f, 0.f, 0.f, 0.f};
#pragma unroll
            for (int kb = 0; kb < 2; ++kb) {
                f16x8 a0[8], a1[8];
#pragma unroll
                for (int kk = 0; kk < 8; ++kk) {
                    int k0 = (kb * 8 + kk) * 32 + fk;
                    a0[kk] = *(const f16x8*)&hs[(size_t)(mbase + frow) * H_ + k0];
                    a1[kk] = *(const f16x8*)&hs[(size_t)(mbase + 16 + frow) * H_ + k0];
                }
#pragma unroll
                for (int kk = 0; kk < 8; ++kk) {
                    f16x8 bv = *(f16x8*)&S->w[nt + frow][(kb * 8 + kk) * 32 + fk];
                    acc0 = __builtin_amdgcn_mfma_f32_16x16x32_f16(a0[kk], bv, acc0, 0, 0, 0);
                    acc1 = __builtin_amdgcn_mfma_f32_16x16x32_f16(a1[kk], bv, acc1, 0, 0, 0);
                }
            }
#pragma unroll
            for (int r = 0; r < 4; ++r) {
                hWhhP[((size_t)(mbase + rq + r) * 512 + cj) * 4 + gate] = acc0[r];
                hWhhP[((size_t)(mbase + 16 + rq + r) * 512 + cj) * 4 + gate] = acc1[r];
            }
            __syncthreads();
            if (tid == 0) {
                __threadfence();
                __hip_atomic_store(&gemmflag[g * SLOT], (unsigned)(t + 1),
                                   __ATOMIC_RELAXED, __HIP_MEMORY_SCOPE_AGENT);
            }
        }
    }
}

// ---------------------------------------------------------------- launch
extern "C" void kernel_launch(void* const* d_in, const int* in_sizes, int n_in,
                              void* d_out, int out_size, void* d_ws, size_t ws_size,
                              hipStream_t stream) {
    const float* image_feats = (const float*)d_in[0];
    const int*   caption     = (const int*)d_in[1];
    const float* embedding   = (const float*)d_in[2];
    const float* W_init_h    = (const float*)d_in[3];
    const float* b_init_h    = (const float*)d_in[4];
    const float* W_init_c    = (const float*)d_in[5];
    const float* b_init_c    = (const float*)d_in[6];
    const float* W_feat      = (const float*)d_in[7];
    const float* b_feat      = (const float*)d_in[8];
    const float* W_hid       = (const float*)d_in[9];
    const float* b_hid       = (const float*)d_in[10];
    const float* W_score     = (const float*)d_in[11];
    const float* b_score     = (const float*)d_in[12];
    const float* W_ih        = (const float*)d_in[13];
    const float* b_ih        = (const float*)d_in[14];
    const float* W_hh        = (const float*)d_in[15];
    const float* b_hh        = (const float*)d_in[16];
    const float* W_out       = (const float*)d_in[17];
    const float* b_out       = (const float*)d_in[18];

    float* preds = (float*)d_out;                                   // (B,T,V)
    float* out_alpha = preds + (size_t)B_ * T_ * V_;                // (B,T,L)

    size_t off = 0;
    char* base = (char*)d_ws;
    auto carve = [&](size_t bytes) {
        void* p = base + off;
        off += (bytes + 255) & ~(size_t)255;
        return p;
    };
    const int MP = 3200;  // B*L=3136 padded to 25*128
    f16* featproj2P = (f16*)carve((size_t)MP * G4 * 2);             // 13.1 MB
    f16* embprojP   = (f16*)carve((size_t)B_ * T_ * G4 * 2);        // 8.4 MB
    float* featproj = (float*)carve((size_t)B_ * L_ * A_ * 4);      // 3.2 MB
    float* hbuf0    = (float*)carve((size_t)B_ * H_ * 4);
    float* c_cur    = (float*)carve((size_t)B_ * H_ * 4);
    float* hWhhP    = (float*)carve((size_t)B_ * G4 * 4);
    unsigned* flags = (unsigned*)carve(128 * SLOT * 4);             // 8 KB
    f16* feats16    = (f16*)carve((size_t)MP * F_ * 2);
    f16* embs16     = (f16*)carve((size_t)B_ * T_ * E_ * 2);
    f16* WihT       = (f16*)carve((size_t)G4 * (E_ + F_) * 2);
    f16* WhhT       = (f16*)carve((size_t)G4 * H_ * 2);
    f16* WoutT      = (f16*)carve((size_t)V_ * H_ * 2);
    f16* Whidp      = (f16*)carve((size_t)H_ * A_ * 2);
    f16* h16rec     = (f16*)carve((size_t)(T_ + 1) * B_ * H_ * 2);
    f16* h16log     = (f16*)carve((size_t)B_ * T_ * H_ * 2);
    unsigned* gateflag = flags;
    unsigned* gemmflag = flags + 64 * SLOT;
    (void)ws_size; (void)in_sizes; (void)n_in; (void)out_size;

    hipLaunchKernelGGL(k_tcvt, dim3(G4 / 32, (E_ + F_) / 32), dim3(256), 0, stream,
                       W_ih, WihT, E_ + F_, G4);
    hipLaunchKernelGGL(k_tcvt, dim3(G4 / 32, H_ / 32), dim3(256), 0, stream,
                       W_hh, WhhT, H_, G4);
    hipLaunchKernelGGL(k_tcvt, dim3(V_ / 32, H_ / 32), dim3(256), 0, stream,
                       W_out, WoutT, H_, V_);
    {
        int n4 = (int)((size_t)B_ * L_ * F_ / 4);
        hipLaunchKernelGGL(k_cvt_f16, dim3((n4 + 255) / 256), dim3(256), 0, stream,
                           image_feats, feats16, n4);
    }
    hipLaunchKernelGGL(k_pairs, dim3(256), dim3(256), 0, stream, W_hid, Whidp);
    hipLaunchKernelGGL(k_emb, dim3(B_ * T_), dim3(E_), 0, stream, embedding, caption, embs16);
    hipLaunchKernelGGL(k_init, dim3(B_), dim3(256), 0, stream,
                       image_feats, W_init_h, b_init_h, W_init_c, b_init_c,
                       hbuf0, h16rec, c_cur);
    hipLaunchKernelGGL(k_featproj, dim3(B_ * L_ / 16), dim3(256), 0, stream,
                       image_feats, W_feat, b_feat, featproj);
    // featproj2P (f16, gate-permuted) = feats @ W_ih[E:,:]
    hipLaunchKernelGGL(HIP_KERNEL_NAME(k_gemm128<1>), dim3(25 * (G4 / 128)), dim3(256), 0, stream,
                       feats16, F_, WihT + E_, E_ + F_,
                       (void*)featproj2P, G4, MP, F_, 25,
                       (const float*)nullptr, (const float*)nullptr);
    // embprojP (f16, gate-permuted) = embs @ W_ih[:E,:] + b_ih + b_hh
    hipLaunchKernelGGL(HIP_KERNEL_NAME(k_gemm128<1>), dim3((B_ * T_ / 128) * (G4 / 128)), dim3(256), 0, stream,
                       embs16, E_, WihT, E_ + F_,
                       (void*)embprojP, G4, B_ * T_, E_, B_ * T_ / 128,
                       b_ih, b_hh);
    // persistent recurrence: 64 gate blocks + 64 hWhh-GEMM blocks, flag handoff
    hipMemsetAsync(flags, 0, 128 * SLOT * 4, stream);
    hipLaunchKernelGGL(k_steps, dim3(128), dim3(256), 0, stream,
                       WhhT, featproj, (const f16x2*)Whidp, b_hid, W_score, b_score,
                       embprojP, featproj2P, hbuf0, c_cur,
                       h16rec, h16log, hWhhP, out_alpha, gateflag, gemmflag);
    // predictions = h16log @ W_out + b_out
    hipLaunchKernelGGL(HIP_KERNEL_NAME(k_gemm128<0>), dim3((B_ * T_ / 128) * (V_ / 128)), dim3(256), 0, stream,
                       h16log, H_, WoutT, H_,
                       (void*)preds, V_, B_ * T_, H_, B_ * T_ / 128,
                       b_out, (const float*)nullptr);
}

// Round 4
// 1016.915 us; speedup vs baseline: 7.7533x; 1.1880x over previous
//
#include <hip/hip_runtime.h>
#include <hip/hip_bf16.h>

typedef _Float16 f16;
typedef _Float16 f16x8 __attribute__((ext_vector_type(8)));
typedef _Float16 f16x4 __attribute__((ext_vector_type(4)));
typedef _Float16 f16x2 __attribute__((ext_vector_type(2)));
typedef float f32x4 __attribute__((ext_vector_type(4)));
typedef unsigned long long ull;

#define B_ 64
#define T_ 32
#define L_ 49
#define F_ 512
#define H_ 512
#define A_ 256
#define E_ 256
#define V_ 32000
#define G4 2048   // 4*H
#define SLOT 16   // flag padding: 16 uints = 64B

#define ALOAD32(p)     __hip_atomic_load((const unsigned*)(p), __ATOMIC_RELAXED, __HIP_MEMORY_SCOPE_AGENT)
#define ALOAD64(p)     __hip_atomic_load((const ull*)(p), __ATOMIC_RELAXED, __HIP_MEMORY_SCOPE_AGENT)
#define ASTORE32(p, v) __hip_atomic_store((unsigned*)(p), (v), __ATOMIC_RELAXED, __HIP_MEMORY_SCOPE_AGENT)
#define ASTOREF(p, v)  __hip_atomic_store((float*)(p), (v), __ATOMIC_RELAXED, __HIP_MEMORY_SCOPE_AGENT)

// ---------------------------------------------------------------- converts
__global__ void k_cvt_f16(const float* __restrict__ x, f16* __restrict__ y, int n4) {
    int i = blockIdx.x * 256 + threadIdx.x;
    if (i < n4) {
        float4 v = ((const float4*)x)[i];
        f16x4 h = {(f16)v.x, (f16)v.y, (f16)v.z, (f16)v.w};
        ((f16x4*)y)[i] = h;
    }
}

// transpose+convert: x f32 [R][C] -> y f16 [C][R]
__global__ void k_tcvt(const float* __restrict__ x, f16* __restrict__ y, int R, int C) {
    __shared__ float ls[32][33];
    int c0 = blockIdx.x * 32, r0 = blockIdx.y * 32;
    int tid = threadIdx.x;
    int rr = tid >> 3, cs = (tid & 7) * 4;
    float4 v = *(const float4*)&x[(size_t)(r0 + rr) * C + c0 + cs];
    ls[rr][cs] = v.x; ls[rr][cs + 1] = v.y; ls[rr][cs + 2] = v.z; ls[rr][cs + 3] = v.w;
    __syncthreads();
    int cr = tid >> 3, rs = (tid & 7) * 4;
    f16x4 o = {(f16)ls[rs][cr], (f16)ls[rs + 1][cr], (f16)ls[rs + 2][cr], (f16)ls[rs + 3][cr]};
    *(f16x4*)&y[(size_t)(c0 + cr) * R + r0 + rs] = o;
}

// W_hid f32 [512][256] -> k-pair packed f16x2 [256][256]
__global__ void k_pairs(const float* __restrict__ w, f16* __restrict__ out) {
    int k2 = blockIdx.x, a = threadIdx.x;
    out[(k2 * 256 + a) * 2]     = (f16)w[(2 * k2) * 256 + a];
    out[(k2 * 256 + a) * 2 + 1] = (f16)w[(2 * k2 + 1) * 256 + a];
}

// embedding gather -> fp16, row r = b*T + t
__global__ void k_emb(const float* __restrict__ emb, const int* __restrict__ cap,
                      f16* __restrict__ out) {
    int r = blockIdx.x;
    int tok = cap[r];
    out[(size_t)r * E_ + threadIdx.x] = (f16)emb[(size_t)tok * E_ + threadIdx.x];
}

// ---------------------------------------------------------------- init h0/c0
__global__ void k_init(const float* __restrict__ feats,
                       const float* __restrict__ Wh, const float* __restrict__ bh,
                       const float* __restrict__ Wc, const float* __restrict__ bc,
                       float* __restrict__ hbuf0, f16* __restrict__ h16rec,
                       float* __restrict__ c_cur) {
    __shared__ float mean[F_];
    int b = blockIdx.x, tid = threadIdx.x;
    for (int f = tid; f < F_; f += 256) {
        float s = 0.f;
        for (int l = 0; l < L_; ++l) s += feats[((size_t)b * L_ + l) * F_ + f];
        mean[f] = s * (1.f / 49.f);
    }
    __syncthreads();
    for (int h = tid; h < H_; h += 256) {
        float a = bh[h], c = bc[h];
        for (int k = 0; k < F_; ++k) {
            float m = mean[k];
            a += m * Wh[k * H_ + h];
            c += m * Wc[k * H_ + h];
        }
        hbuf0[b * H_ + h] = a;
        h16rec[b * H_ + h] = (f16)a;
        c_cur[b * H_ + h] = c;
    }
}

// ---------------------------------------------------------------- feat_proj (fp32)
__global__ void k_featproj(const float* __restrict__ feats, const float* __restrict__ Wf,
                           const float* __restrict__ bf, float* __restrict__ out) {
    __shared__ float fs[16][F_];
    int r0 = blockIdx.x * 16, tid = threadIdx.x;
    for (int i = tid; i < 16 * F_; i += 256)
        fs[i >> 9][i & 511] = feats[(size_t)r0 * F_ + i];
    __syncthreads();
    float acc[16];
#pragma unroll
    for (int r = 0; r < 16; ++r) acc[r] = 0.f;
    for (int k = 0; k < F_; ++k) {
        float w = Wf[k * A_ + tid];
#pragma unroll
        for (int r = 0; r < 16; ++r) acc[r] += fs[r][k] * w;
    }
    float bb = bf[tid];
#pragma unroll
    for (int r = 0; r < 16; ++r) out[(size_t)(r0 + r) * A_ + tid] = acc[r] + bb;
}

// ---------------------------------------------------------------- 128x128 MFMA GEMM
// MODE 0: C f32 [rr*ldc+cc] + bias   MODE 1: C f16 gate-permuted [(rr*512+(cc&511))*4+(cc>>9)]
struct Smem128 { f16 As[128][40]; f16 Bs[128][40]; };

template <int MODE>
__global__ __launch_bounds__(256) void k_gemm128(
    const f16* __restrict__ A, int lda, const f16* __restrict__ Bt, int ldb,
    void* __restrict__ Cv, int ldc, int M, int K, int mtiles,
    const float* __restrict__ bias0, const float* __restrict__ bias1) {
    __shared__ Smem128 sm;
    int bid = blockIdx.x;
    int m0 = (bid % mtiles) * 128, n0 = (bid / mtiles) * 128;
    int tid = threadIdx.x, lane = tid & 63, wave = tid >> 6;
    int wr = (wave >> 1) * 64, wc = (wave & 1) * 64;
    int frow = lane & 15, fk = (lane >> 4) * 8;
    int ra = tid >> 2, ka = (tid & 3) * 8;
    f32x4 acc[4][4];
#pragma unroll
    for (int i = 0; i < 4; ++i)
#pragma unroll
        for (int j = 0; j < 4; ++j) { acc[i][j][0]=0.f; acc[i][j][1]=0.f; acc[i][j][2]=0.f; acc[i][j][3]=0.f; }

    for (int k0 = 0; k0 < K; k0 += 32) {
        f16x8 a0 = *(const f16x8*)&A[(size_t)(m0 + ra) * lda + k0 + ka];
        f16x8 a1 = *(const f16x8*)&A[(size_t)(m0 + 64 + ra) * lda + k0 + ka];
        f16x8 b0 = *(const f16x8*)&Bt[(size_t)(n0 + ra) * ldb + k0 + ka];
        f16x8 b1 = *(const f16x8*)&Bt[(size_t)(n0 + 64 + ra) * ldb + k0 + ka];
        __syncthreads();
        *(f16x8*)&sm.As[ra][ka] = a0;
        *(f16x8*)&sm.As[64 + ra][ka] = a1;
        *(f16x8*)&sm.Bs[ra][ka] = b0;
        *(f16x8*)&sm.Bs[64 + ra][ka] = b1;
        __syncthreads();
        f16x8 av[4], bv[4];
#pragma unroll
        for (int i = 0; i < 4; ++i) {
            av[i] = *(f16x8*)&sm.As[wr + i * 16 + frow][fk];
            bv[i] = *(f16x8*)&sm.Bs[wc + i * 16 + frow][fk];
        }
#pragma unroll
        for (int mi = 0; mi < 4; ++mi)
#pragma unroll
            for (int ni = 0; ni < 4; ++ni)
                acc[mi][ni] = __builtin_amdgcn_mfma_f32_16x16x32_f16(av[mi], bv[ni], acc[mi][ni], 0, 0, 0);
    }
    int rq = (lane >> 4) * 4;
#pragma unroll
    for (int mi = 0; mi < 4; ++mi)
#pragma unroll
        for (int ni = 0; ni < 4; ++ni) {
            int cc = n0 + wc + ni * 16 + frow;
            float badd = (bias0 ? bias0[cc] : 0.f) + (bias1 ? bias1[cc] : 0.f);
#pragma unroll
            for (int r = 0; r < 4; ++r) {
                int rr = m0 + wr + mi * 16 + rq + r;
                if (rr < M) {
                    if (MODE == 0)
                        ((float*)Cv)[(size_t)rr * ldc + cc] = acc[mi][ni][r] + badd;
                    else
                        ((f16*)Cv)[((size_t)rr * 512 + (cc & 511)) * 4 + (cc >> 9)] =
                            (f16)(acc[mi][ni][r] + badd);
                }
            }
        }
}

// ---------------------------------------------------------------- persistent recurrence
struct GateSm {
    float fp[L_][A_];    // 50176 B
    float h[H_];         // 2 KB
    float c[H_];         // 2 KB
    float ea[A_];        // 1 KB
    float ws[A_];        // 1 KB
    float sc[64];
    float alpha[64];
};                       // 56832 B
struct GemmSm {
    f16 w[32][552];      // 35328 B (552 f16 stride: 2-way max on ds_read)
    f16 hs[64][528];     // 67584 B h-stage (528 f16 = 264 dw = 8 mod 32 banks)
};                       // 102912 B

// fence-free: poll flags with relaxed agent loads; data moves via sc1 atomics,
// so no cache invalidate is ever needed (read-only streams stay in L2).
__device__ __forceinline__ void wait_all(const unsigned* flags, unsigned target) {
    int l = threadIdx.x & 63;
    const unsigned* p = flags + l * SLOT;
    int spins = 0;
    while (__hip_atomic_load(p, __ATOMIC_RELAXED, __HIP_MEMORY_SCOPE_AGENT) < target) {
        if (++spins > 16) __builtin_amdgcn_s_sleep(1);
    }
    asm volatile("" ::: "memory");   // keep data loads after the poll
}

__device__ __forceinline__ float sigm(float x) { return 1.f / (1.f + __expf(-x)); }
__device__ __forceinline__ float tanh_f(float x) { return 1.f - 2.f / (1.f + __expf(2.f * x)); }

__global__ __launch_bounds__(256, 1) void k_steps(
    const f16* __restrict__ WhhT, const float* __restrict__ featproj,
    const f16x2* __restrict__ Whidp, const float* __restrict__ b_hid,
    const float* __restrict__ W_score, const float* __restrict__ b_score,
    const f16* __restrict__ embprojP, const f16* __restrict__ featproj2P,
    const float* __restrict__ hbuf0, const float* __restrict__ c_cur,
    f16* __restrict__ h16rec, f16* __restrict__ h16log,
    float* __restrict__ hWhhP, float* __restrict__ out_alpha,
    unsigned* __restrict__ gateflag, unsigned* __restrict__ gemmflag) {
    __shared__ __align__(16) char smraw[sizeof(GemmSm)];
    int bid = blockIdx.x, tid = threadIdx.x;

    if (bid < 64) {
        // ============ gate/attention block for batch b ============
        int b = bid;
        GateSm* S = (GateSm*)smraw;
        for (int i = tid; i < L_ * A_; i += 256)
            ((float*)S->fp)[i] = featproj[(size_t)b * L_ * A_ + i];
        for (int i = tid; i < H_; i += 256) {
            S->h[i] = hbuf0[b * H_ + i];
            S->c[i] = c_cur[b * H_ + i];
        }
        S->ws[tid] = W_score[tid];
        float bhid_r = b_hid[tid];
        float bsc = b_score[0];
        __syncthreads();

        const float2* h2 = (const float2*)S->h;
        int wv = tid >> 6, ln = tid & 63;
        int j0 = 2 * tid;   // this thread's two gate columns

        for (int t = 0; t < T_; ++t) {
            // ---- ea = h @ W_hid + b_hid (thread = attn col) ----
            float acc = bhid_r;
#pragma unroll 8
            for (int k2 = 0; k2 < 256; ++k2) {
                f16x2 w = Whidp[k2 * 256 + tid];
                float2 hp = h2[k2];
                acc += hp.x * (float)w.x + hp.y * (float)w.y;
            }
            S->ea[tid] = acc;
            __syncthreads();
            // ---- scores ----
            for (int l = wv; l < L_; l += 4) {
                float p = 0.f;
#pragma unroll
                for (int q = 0; q < 4; ++q) {
                    int j = ln + q * 64;
                    p += tanh_f(S->fp[l][j] + S->ea[j]) * S->ws[j];
                }
#pragma unroll
                for (int off = 32; off > 0; off >>= 1) p += __shfl_xor(p, off);
                if (ln == 0) S->sc[l] = p;
            }
            __syncthreads();
            // ---- softmax (wave 0) ----
            if (tid < 64) {
                float v = (tid < L_) ? S->sc[tid] + bsc : -3.4e38f;
                float m = v;
#pragma unroll
                for (int off = 32; off > 0; off >>= 1) m = fmaxf(m, __shfl_xor(m, off));
                float e = (tid < L_) ? __expf(v - m) : 0.f;
                float s = e;
#pragma unroll
                for (int off = 32; off > 0; off >>= 1) s += __shfl_xor(s, off);
                if (tid < L_) {
                    float al = e / s;
                    S->alpha[tid] = al;
                    out_alpha[((size_t)b * T_ + t) * L_ + tid] = al;
                }
            }
            __syncthreads();
            // ---- wait recurrent matmul for this step ----
            wait_all(gemmflag, (unsigned)(t + 1));
            // ---- gates + pointwise; thread owns cols j0, j0+1 ----
            {
                size_t hwb = ((size_t)b * 512 + j0) * 4;
                ull v0 = ALOAD64(&hWhhP[hwb]);
                ull v1 = ALOAD64(&hWhhP[hwb + 2]);
                ull v2 = ALOAD64(&hWhhP[hwb + 4]);
                ull v3 = ALOAD64(&hWhhP[hwb + 6]);
                float2 p0 = *(float2*)&v0, p1 = *(float2*)&v1;
                float2 p2 = *(float2*)&v2, p3 = *(float2*)&v3;
                f16x8 ep = *(const f16x8*)&embprojP[(((size_t)b * T_ + t) * 512 + j0) * 4];
                float gi0 = p0.x + (float)ep[0], gf0 = p0.y + (float)ep[1];
                float gg0 = p1.x + (float)ep[2], go0 = p1.y + (float)ep[3];
                float gi1 = p2.x + (float)ep[4], gf1 = p2.y + (float)ep[5];
                float gg1 = p3.x + (float)ep[6], go1 = p3.y + (float)ep[7];
                const f16* fpb = featproj2P + ((size_t)b * L_) * G4 + j0 * 4;
#pragma unroll 7
                for (int l = 0; l < L_; ++l) {
                    float a = S->alpha[l];
                    f16x8 fv = *(const f16x8*)&fpb[(size_t)l * G4];
                    gi0 += a * (float)fv[0]; gf0 += a * (float)fv[1];
                    gg0 += a * (float)fv[2]; go0 += a * (float)fv[3];
                    gi1 += a * (float)fv[4]; gf1 += a * (float)fv[5];
                    gg1 += a * (float)fv[6]; go1 += a * (float)fv[7];
                }
                float cn0 = sigm(gf0) * S->c[j0]     + sigm(gi0) * tanh_f(gg0);
                float cn1 = sigm(gf1) * S->c[j0 + 1] + sigm(gi1) * tanh_f(gg1);
                float hn0 = sigm(go0) * tanh_f(cn0);
                float hn1 = sigm(go1) * tanh_f(cn1);
                S->c[j0] = cn0; S->c[j0 + 1] = cn1;
                S->h[j0] = hn0; S->h[j0 + 1] = hn1;
                union { f16 h[2]; unsigned u; } pk;
                pk.h[0] = (f16)hn0; pk.h[1] = (f16)hn1;
                ASTORE32((unsigned*)h16rec + ((size_t)(t + 1) * B_ + b) * 256 + tid, pk.u);
                ((unsigned*)h16log)[((size_t)b * T_ + t) * 256 + tid] = pk.u;
            }
            __syncthreads();   // drains vmcnt: sc1 h-stores are at coherence point
            if (tid == 0)
                ASTORE32(&gateflag[b * SLOT], (unsigned)(t + 1));
        }
    } else {
        // ============ hWhh GEMM block: 32-col slice of 4H ============
        int g = bid - 64;
        int n0 = g * 32;
        GemmSm* S = (GemmSm*)smraw;
        for (int idx = tid; idx < 32 * 64; idx += 256) {
            int r = idx >> 6, s = idx & 63;
            *(f16x8*)&S->w[r][s * 8] = *(const f16x8*)&WhhT[(size_t)(n0 + r) * H_ + s * 8];
        }
        __syncthreads();
        int wv = tid >> 6, lane = tid & 63;
        int frow = lane & 15, q = lane >> 4, fk = q * 8;
        int mbase = (wv >> 1) * 32, nt = (wv & 1) * 16;
        int col = n0 + nt + frow;
        int gate = col >> 9, cj = col & 511;
        int rq = q * 4;

        for (int t = 0; t < T_; ++t) {
            wait_all(gateflag, (unsigned)t);
            // stage h16rec[t] (64x512 f16) into LDS via sc1 loads
            {
                const unsigned* hsrc = (const unsigned*)h16rec + (size_t)t * B_ * 256;
#pragma unroll 8
                for (int c = 0; c < 64; ++c) {
                    unsigned v = ALOAD32(hsrc + c * 256 + tid);
                    *(unsigned*)&S->hs[c][2 * tid] = v;
                }
            }
            __syncthreads();
            f32x4 acc0 = {0.f, 0.f, 0.f, 0.f}, acc1 = {0.f, 0.f, 0.f, 0.f};
#pragma unroll
            for (int kk = 0; kk < 16; ++kk) {
                int k0 = kk * 32 + fk;
                f16x8 av0 = *(f16x8*)&S->hs[mbase + frow][k0];
                f16x8 av1 = *(f16x8*)&S->hs[mbase + 16 + frow][k0];
                f16x8 bv  = *(f16x8*)&S->w[nt + frow][k0];
                acc0 = __builtin_amdgcn_mfma_f32_16x16x32_f16(av0, bv, acc0, 0, 0, 0);
                acc1 = __builtin_amdgcn_mfma_f32_16x16x32_f16(av1, bv, acc1, 0, 0, 0);
            }
#pragma unroll
            for (int r = 0; r < 4; ++r) {
                ASTOREF(&hWhhP[((size_t)(mbase + rq + r) * 512 + cj) * 4 + gate], acc0[r]);
                ASTOREF(&hWhhP[((size_t)(mbase + 16 + rq + r) * 512 + cj) * 4 + gate], acc1[r]);
            }
            __syncthreads();   // drains vmcnt: hWhh sc1 stores visible
            if (tid == 0)
                ASTORE32(&gemmflag[g * SLOT], (unsigned)(t + 1));
        }
    }
}

// ---------------------------------------------------------------- launch
extern "C" void kernel_launch(void* const* d_in, const int* in_sizes, int n_in,
                              void* d_out, int out_size, void* d_ws, size_t ws_size,
                              hipStream_t stream) {
    const float* image_feats = (const float*)d_in[0];
    const int*   caption     = (const int*)d_in[1];
    const float* embedding   = (const float*)d_in[2];
    const float* W_init_h    = (const float*)d_in[3];
    const float* b_init_h    = (const float*)d_in[4];
    const float* W_init_c    = (const float*)d_in[5];
    const float* b_init_c    = (const float*)d_in[6];
    const float* W_feat      = (const float*)d_in[7];
    const float* b_feat      = (const float*)d_in[8];
    const float* W_hid       = (const float*)d_in[9];
    const float* b_hid       = (const float*)d_in[10];
    const float* W_score     = (const float*)d_in[11];
    const float* b_score     = (const float*)d_in[12];
    const float* W_ih        = (const float*)d_in[13];
    const float* b_ih        = (const float*)d_in[14];
    const float* W_hh        = (const float*)d_in[15];
    const float* b_hh        = (const float*)d_in[16];
    const float* W_out       = (const float*)d_in[17];
    const float* b_out       = (const float*)d_in[18];

    float* preds = (float*)d_out;                                   // (B,T,V)
    float* out_alpha = preds + (size_t)B_ * T_ * V_;                // (B,T,L)

    size_t off = 0;
    char* base = (char*)d_ws;
    auto carve = [&](size_t bytes) {
        void* p = base + off;
        off += (bytes + 255) & ~(size_t)255;
        return p;
    };
    const int MP = 3200;  // B*L=3136 padded to 25*128
    f16* featproj2P = (f16*)carve((size_t)MP * G4 * 2);             // 13.1 MB
    f16* embprojP   = (f16*)carve((size_t)B_ * T_ * G4 * 2);        // 8.4 MB
    float* featproj = (float*)carve((size_t)B_ * L_ * A_ * 4);      // 3.2 MB
    float* hbuf0    = (float*)carve((size_t)B_ * H_ * 4);
    float* c_cur    = (float*)carve((size_t)B_ * H_ * 4);
    float* hWhhP    = (float*)carve((size_t)B_ * G4 * 4);
    unsigned* flags = (unsigned*)carve(128 * SLOT * 4);             // 8 KB
    f16* feats16    = (f16*)carve((size_t)MP * F_ * 2);
    f16* embs16     = (f16*)carve((size_t)B_ * T_ * E_ * 2);
    f16* WihT       = (f16*)carve((size_t)G4 * (E_ + F_) * 2);
    f16* WhhT       = (f16*)carve((size_t)G4 * H_ * 2);
    f16* WoutT      = (f16*)carve((size_t)V_ * H_ * 2);
    f16* Whidp      = (f16*)carve((size_t)H_ * A_ * 2);
    f16* h16rec     = (f16*)carve((size_t)(T_ + 1) * B_ * H_ * 2);
    f16* h16log     = (f16*)carve((size_t)B_ * T_ * H_ * 2);
    unsigned* gateflag = flags;
    unsigned* gemmflag = flags + 64 * SLOT;
    (void)ws_size; (void)in_sizes; (void)n_in; (void)out_size;

    hipLaunchKernelGGL(k_tcvt, dim3(G4 / 32, (E_ + F_) / 32), dim3(256), 0, stream,
                       W_ih, WihT, E_ + F_, G4);
    hipLaunchKernelGGL(k_tcvt, dim3(G4 / 32, H_ / 32), dim3(256), 0, stream,
                       W_hh, WhhT, H_, G4);
    hipLaunchKernelGGL(k_tcvt, dim3(V_ / 32, H_ / 32), dim3(256), 0, stream,
                       W_out, WoutT, H_, V_);
    {
        int n4 = (int)((size_t)B_ * L_ * F_ / 4);
        hipLaunchKernelGGL(k_cvt_f16, dim3((n4 + 255) / 256), dim3(256), 0, stream,
                           image_feats, feats16, n4);
    }
    hipLaunchKernelGGL(k_pairs, dim3(256), dim3(256), 0, stream, W_hid, Whidp);
    hipLaunchKernelGGL(k_emb, dim3(B_ * T_), dim3(E_), 0, stream, embedding, caption, embs16);
    hipLaunchKernelGGL(k_init, dim3(B_), dim3(256), 0, stream,
                       image_feats, W_init_h, b_init_h, W_init_c, b_init_c,
                       hbuf0, h16rec, c_cur);
    hipLaunchKernelGGL(k_featproj, dim3(B_ * L_ / 16), dim3(256), 0, stream,
                       image_feats, W_feat, b_feat, featproj);
    // featproj2P (f16, gate-permuted) = feats @ W_ih[E:,:]
    hipLaunchKernelGGL(HIP_KERNEL_NAME(k_gemm128<1>), dim3(25 * (G4 / 128)), dim3(256), 0, stream,
                       feats16, F_, WihT + E_, E_ + F_,
                       (void*)featproj2P, G4, MP, F_, 25,
                       (const float*)nullptr, (const float*)nullptr);
    // embprojP (f16, gate-permuted) = embs @ W_ih[:E,:] + b_ih + b_hh
    hipLaunchKernelGGL(HIP_KERNEL_NAME(k_gemm128<1>), dim3((B_ * T_ / 128) * (G4 / 128)), dim3(256), 0, stream,
                       embs16, E_, WihT, E_ + F_,
                       (void*)embprojP, G4, B_ * T_, E_, B_ * T_ / 128,
                       b_ih, b_hh);
    // persistent recurrence: 64 gate blocks + 64 hWhh-GEMM blocks, fence-free handoff
    hipMemsetAsync(flags, 0, 128 * SLOT * 4, stream);
    hipLaunchKernelGGL(k_steps, dim3(128), dim3(256), 0, stream,
                       WhhT, featproj, (const f16x2*)Whidp, b_hid, W_score, b_score,
                       embprojP, featproj2P, hbuf0, c_cur,
                       h16rec, h16log, hWhhP, out_alpha, gateflag, gemmflag);
    // predictions = h16log @ W_out + b_out
    hipLaunchKernelGGL(HIP_KERNEL_NAME(k_gemm128<0>), dim3((B_ * T_ / 128) * (V_ / 128)), dim3(256), 0, stream,
                       h16log, H_, WoutT, H_,
                       (void*)preds, V_, B_ * T_, H_, B_ * T_ / 128,
                       b_out, (const float*)nullptr);
}